// Round 6
// baseline (289.263 us; speedup 1.0000x reference)
//
#include <hip/hip_runtime.h>
#include <hip/hip_bf16.h>

#define D 128
#define LR 0.025f
#define NCE_BIAS 11.512925464970229f      // log(100000)
#define NCE_NEG_BIAS 9.903487552536127f   // log(100000/5)
#define LUT_SIZE 1202

__device__ __forceinline__ float wave_allreduce(float x) {
    #pragma unroll
    for (int m = 32; m >= 1; m >>= 1) x += __shfl_xor(x, m, 64);
    return x;
}

// Analytic stand-in for the reference's LUT sigmoid (centered quantization err <=1.25e-3).
__device__ __forceinline__ float fast_sig(float x) {
    x = fminf(fmaxf(x, -6.0f), 6.0f) - 0.005f;
    float e = __expf(-x);
    return __builtin_amdgcn_rcpf(1.0f + e);
}

__device__ __forceinline__ float fast_sig_lut(float s, const float* __restrict__ lut) {
    s = fminf(fmaxf(s, -6.0f), 6.0f);
    int idx = (int)floorf((s + 6.01f) / 0.01f);
    idx = min(max(idx, 0), LUT_SIZE - 1);
    return lut[idx];
}

__device__ __forceinline__ unsigned int bf16_rne(float f) {
    unsigned int u = __float_as_uint(f);
    return (u + 0x7FFFu + ((u >> 16) & 1u)) >> 16;
}

// ---------------- fused W->bf16 shadow + degree histogram ----------------
__global__ __launch_bounds__(256) void convhist_kernel(
    const float* __restrict__ W, unsigned short* __restrict__ w16, int n32, int cb,
    const int* __restrict__ ipu, const int* __restrict__ ipv,
    const int* __restrict__ inv,
    int Np, int Nn, int NEG, int2* __restrict__ cnt2)
{
    int b = blockIdx.x;
    if (b < cb) {
        int g = b * 256 + threadIdx.x;
        if (g >= n32) return;
        float4 v = ((const float4*)W)[g];
        uint2 h;
        h.x = bf16_rne(v.x) | (bf16_rne(v.y) << 16);
        h.y = bf16_rne(v.z) | (bf16_rne(v.w) << 16);
        ((uint2*)w16)[g] = h;
    } else {
        int t = (b - cb) * 256 + threadIdx.x;
        if (t < Np) {
            atomicAdd((unsigned long long*)&cnt2[ipu[t]],
                      1ull + ((unsigned long long)NEG << 32));
            atomicAdd(&cnt2[ipv[t]].x, 1);
        } else if (t < Np + Nn) {
            int k = t - Np;
            atomicAdd(&cnt2[inv[k]].y, 1);
        }
    }
}

// ---------------- single-pass dual exclusive scan (decoupled lookback) ----
__global__ __launch_bounds__(256) void scan_fused(
    const int2* __restrict__ cnt2,
    int* __restrict__ off_p, int* __restrict__ off_n, int2* __restrict__ cur2,
    unsigned long long* __restrict__ partials, int* __restrict__ ticket, int n)
{
    __shared__ int shp[256], shn[256];
    __shared__ int tkt_s;
    if (threadIdx.x == 0) tkt_s = atomicAdd(ticket, 1);
    __syncthreads();
    const int t = tkt_s;

    int g = t * 256 + threadIdx.x;
    int2 x = (g < n) ? cnt2[g] : make_int2(0, 0);
    shp[threadIdx.x] = x.x;
    shn[threadIdx.x] = x.y;
    __syncthreads();
    #pragma unroll
    for (int d = 1; d < 256; d <<= 1) {
        int tp = (threadIdx.x >= d) ? shp[threadIdx.x - d] : 0;
        int tn = (threadIdx.x >= d) ? shn[threadIdx.x - d] : 0;
        __syncthreads();
        shp[threadIdx.x] += tp;
        shn[threadIdx.x] += tn;
        __syncthreads();
    }
    int incP = shp[threadIdx.x];          // inclusive local scan
    int incN = shn[threadIdx.x];

    if (threadIdx.x == 255) {
        unsigned long long v = (unsigned long long)(unsigned int)(incP + 1)
                             | ((unsigned long long)(unsigned int)incN << 32);
        atomicExch(&partials[t], v);      // atomic 64-bit publish (agg+flag in one word)
    }

    // lookback: sum aggregates of all predecessor tickets
    int myP = 0, myN = 0;
    for (int i = threadIdx.x; i < t; i += 256) {
        unsigned long long v;
        do {
            v = atomicAdd(&partials[i], 0ull);     // device-scope atomic read
        } while ((v & 0xFFFFFFFFull) == 0ull);
        myP += (int)(v & 0xFFFFFFFFull) - 1;
        myN += (int)(v >> 32);
    }
    __syncthreads();                       // shp/shn free for reuse
    shp[threadIdx.x] = myP;
    shn[threadIdx.x] = myN;
    __syncthreads();
    #pragma unroll
    for (int d = 128; d > 0; d >>= 1) {
        if (threadIdx.x < d) {
            shp[threadIdx.x] += shp[threadIdx.x + d];
            shn[threadIdx.x] += shn[threadIdx.x + d];
        }
        __syncthreads();
    }
    const int baseP = shp[0];
    const int baseN = shn[0];

    if (g < n) {
        int vp = incP - x.x + baseP;       // exclusive + global base
        int vn = incN - x.y + baseN;
        off_p[g] = vp;
        off_n[g] = vn;
        cur2[g] = make_int2(vp, vn);
    }
}

// pos pair t: ONE 64-bit atomic reserves the u-side pos slot AND NEG contiguous
// neg slots; neg partners written contiguously.
__global__ __launch_bounds__(256) void fill_kernel(
    const int* __restrict__ ipu, const int* __restrict__ ipv,
    const int* __restrict__ inu, const int* __restrict__ inv,
    int Np, int Nn, int NEG,
    int2* __restrict__ cur2, int* __restrict__ ent_p, int* __restrict__ ent_n)
{
    int t = blockIdx.x * 256 + threadIdx.x;
    if (t < Np) {
        int u = ipu[t], v = ipv[t];
        unsigned long long pk = atomicAdd((unsigned long long*)&cur2[u],
                                          1ull + ((unsigned long long)NEG << 32));
        int slot_pu = (int)(pk & 0xFFFFFFFFull);
        int slot_nu = (int)(pk >> 32);
        ent_p[slot_pu] = v;
        for (int j = 0; j < NEG; ++j)
            ent_n[slot_nu + j] = inv[(size_t)NEG * t + j];
        ent_p[atomicAdd(&cur2[v].x, 1)] = u;
    } else if (t < Np + Nn) {
        int k = t - Np;
        ent_n[atomicAdd(&cur2[inv[k]].y, 1)] = inu[k];
    }
}

// ---------------- pull update (multi-node batched half-waves) -------------
// Half-wave (32 lanes x float4) processes KPH consecutive nodes instead of 1.
// Rationale (R6): per-node degree is ~Poisson (pos mean 2, neg mean 10);
// with 1 node/half-wave a block's lifetime = max over its 8 nodes' degrees
// => ~0.65 utilization (matches VALUBusy 65%). Batching 8 nodes/half-wave
// sums 8 draws (sqrt(8)x lower relative spread), amortizes prologue costs,
// and shrinks the grid 12500->1563 blocks.
// Inner loop is R2's exact best-known body (54.4us): 4-wide groups, clamped
// prefetch (overruns re-hit L1), 64-bit indexed addressing, no unroll
// pragma, select-exchange multi-reduce (bit-identical xor tree 16,8,4,2,1).
template<bool EMIT16>
__global__ __launch_bounds__(256) void update_kernel(
    const float* __restrict__ baseSrc,
    const unsigned short* __restrict__ partnerH,
    float* __restrict__ dst, unsigned short* __restrict__ dst16,
    const int* __restrict__ offArr, const int* __restrict__ endArr2, int comp,
    const int* __restrict__ entries, int N, int KPH, float bias, float cpos)
{
    int gtid = blockIdx.x * 256 + threadIdx.x;
    int hw   = gtid >> 5;               // global half-wave id
    int hl   = threadIdx.x & 31;

    const bool b3 = (hl & 8) != 0;
    const bool b4 = (hl & 16) != 0;
    const int i_lane = (hl >> 3) & 3;   // which entry's dot this lane owns post-reduce
    const uint2* __restrict__ ph = (const uint2*)partnerH;

    int node0 = hw * KPH;
    for (int j = 0; j < KPH; ++j) {
        int node = node0 + j;
        if (node >= N) break;

        float4 base = ((const float4*)baseSrc)[(size_t)node * 32 + hl];
        float ax = 0.0f, ay = 0.0f, az = 0.0f, aw = 0.0f;

        int beg = offArr[node];
        int len = endArr2[2 * node + comp] - beg;

        if (len > 0) {
            int gcount = (len + 3) >> 2;
            int en[4];
            uint2 rc[4];
            #pragma unroll
            for (int i = 0; i < 4; ++i) {
                int t = min(i, len - 1);
                rc[i] = ph[(size_t)entries[beg + t] * 32 + hl];
            }
            #pragma unroll
            for (int i = 0; i < 4; ++i) {
                int t = min(4 + i, len - 1);
                en[i] = entries[beg + t];
            }
            for (int g = 0; g < gcount; ++g) {
                uint2 rn[4];
                #pragma unroll
                for (int i = 0; i < 4; ++i) rn[i] = ph[(size_t)en[i] * 32 + hl];
                int en2[4];
                #pragma unroll
                for (int i = 0; i < 4; ++i) {
                    int t = (g + 2) * 4 + i;
                    t = (t < len) ? t : (len - 1);
                    en2[i] = entries[beg + t];
                }
                float4 r[4];
                float d[4];
                #pragma unroll
                for (int i = 0; i < 4; ++i) {
                    r[i].x = __uint_as_float(rc[i].x << 16);
                    r[i].y = __uint_as_float(rc[i].x & 0xFFFF0000u);
                    r[i].z = __uint_as_float(rc[i].y << 16);
                    r[i].w = __uint_as_float(rc[i].y & 0xFFFF0000u);
                    d[i] = r[i].x * base.x + r[i].y * base.y + r[i].z * base.z + r[i].w * base.w;
                }
                // ---- select-exchange multi-reduce (same xor tree as before) ----
                float y0 = b4 ? d[0] : d[2];
                float y1 = b4 ? d[1] : d[3];
                y0 = __shfl_xor(y0, 16, 64);
                y1 = __shfl_xor(y1, 16, 64);
                float pa = (b4 ? d[2] : d[0]) + y0;
                float pb = (b4 ? d[3] : d[1]) + y1;
                float y2 = b3 ? pa : pb;
                y2 = __shfl_xor(y2, 8, 64);
                float cc = (b3 ? pb : pa) + y2;
                cc += __shfl_xor(cc, 4, 64);
                cc += __shfl_xor(cc, 2, 64);
                cc += __shfl_xor(cc, 1, 64);

                // ---- one score per lane (lane class b4,b3 owns entry 2*b4+b3) ----
                float s = (g * 4 + i_lane < len)
                            ? (cpos - fast_sig(cc - bias)) * LR : 0.0f;

                // ---- broadcast 4 scores to all lanes ----
                float t8  = __shfl_xor(s, 8, 64);
                float t16 = __shfl_xor(s, 16, 64);
                float t24 = __shfl_xor(t8, 16, 64);
                float p  = b3 ? t8  : s;
                float q  = b3 ? s   : t8;
                float p2 = b3 ? t24 : t16;
                float q2 = b3 ? t16 : t24;
                float se[4];
                se[0] = b4 ? p2 : p;
                se[1] = b4 ? q2 : q;
                se[2] = b4 ? p  : p2;
                se[3] = b4 ? q  : q2;

                #pragma unroll
                for (int i = 0; i < 4; ++i) {
                    ax += se[i] * r[i].x;
                    ay += se[i] * r[i].y;
                    az += se[i] * r[i].z;
                    aw += se[i] * r[i].w;
                }
                #pragma unroll
                for (int i = 0; i < 4; ++i) { rc[i] = rn[i]; en[i] = en2[i]; }
            }
        }
        float4 o = make_float4(base.x + ax, base.y + ay, base.z + az, base.w + aw);
        ((float4*)dst)[(size_t)node * 32 + hl] = o;
        if (EMIT16) {
            uint2 h;
            h.x = bf16_rne(o.x) | (bf16_rne(o.y) << 16);
            h.y = bf16_rne(o.z) | (bf16_rne(o.w) << 16);
            ((uint2*)dst16)[(size_t)node * 32 + hl] = h;
        }
    }
}

// ---------------- fallback scatter path (round-1, known-good) ----------------
__global__ __launch_bounds__(256) void pos_kernel(
    const float* __restrict__ Worig, float* __restrict__ W,
    const float* __restrict__ lut,
    const int* __restrict__ idx_u, const int* __restrict__ idx_v, int n)
{
    int wave = (int)((blockIdx.x * blockDim.x + threadIdx.x) >> 6);
    int lane = threadIdx.x & 63;
    if (wave >= n) return;
    int u = idx_u[wave];
    int v = idx_v[wave];
    float2 eu = ((const float2*)(Worig + (size_t)u * D))[lane];
    float2 ev = ((const float2*)(Worig + (size_t)v * D))[lane];
    float dot = wave_allreduce(eu.x * ev.x + eu.y * ev.y);
    float s = (1.0f - fast_sig_lut(dot - NCE_BIAS, lut)) * LR;
    float* wu = W + (size_t)u * D;
    float* wv = W + (size_t)v * D;
    atomicAdd(&wu[2 * lane],     s * ev.x);
    atomicAdd(&wu[2 * lane + 1], s * ev.y);
    atomicAdd(&wv[2 * lane],     s * eu.x);
    atomicAdd(&wv[2 * lane + 1], s * eu.y);
}

__global__ __launch_bounds__(256) void neg_kernel(
    const float* __restrict__ Wsnap, float* __restrict__ W,
    const float* __restrict__ lut,
    const int* __restrict__ idx_u, const int* __restrict__ idx_v, int n, int neg)
{
    int wave = (int)((blockIdx.x * blockDim.x + threadIdx.x) >> 6);
    int lane = threadIdx.x & 63;
    if (wave >= n) return;
    int u = idx_u[wave * neg];
    float2 eu = ((const float2*)(Wsnap + (size_t)u * D))[lane];
    float dux = 0.0f, duy = 0.0f;
    for (int j = 0; j < neg; ++j) {
        int v = idx_v[wave * neg + j];
        float2 ev = ((const float2*)(Wsnap + (size_t)v * D))[lane];
        float dot = wave_allreduce(eu.x * ev.x + eu.y * ev.y);
        float s = -fast_sig_lut(dot - NCE_NEG_BIAS, lut) * LR;
        dux += s * ev.x;
        duy += s * ev.y;
        float* wv = W + (size_t)v * D;
        atomicAdd(&wv[2 * lane],     s * eu.x);
        atomicAdd(&wv[2 * lane + 1], s * eu.y);
    }
    float* wu = W + (size_t)u * D;
    atomicAdd(&wu[2 * lane],     dux);
    atomicAdd(&wu[2 * lane + 1], duy);
}

extern "C" void kernel_launch(void* const* d_in, const int* in_sizes, int n_in,
                              void* d_out, int out_size, void* d_ws, size_t ws_size,
                              hipStream_t stream) {
    const float* W   = (const float*)d_in[0];
    const float* lut = (const float*)d_in[1];
    const int* ipu   = (const int*)d_in[2];
    const int* ipv   = (const int*)d_in[3];
    const int* inu   = (const int*)d_in[4];
    const int* inv   = (const int*)d_in[5];
    float* out = (float*)d_out;

    const int N  = in_sizes[0] / D;        // nodes
    const int Np = in_sizes[2];            // positive pairs
    const int Nn = in_sizes[4];            // negative pairs (N*NEG)
    const int NEG = Nn / Np;
    const size_t WB = (size_t)N * D * sizeof(float);
    const int nb = (N + 255) / 256;
    const int n_entp = 2 * Np;
    const int n_entn = NEG * Np + Nn;

    size_t need = (size_t)N * D * 2 * 2                       // w16W + w16P
                + (size_t)n_entp * 4 + (size_t)n_entn * 4
                + 64                                          // zero pad after ent_n
                + (size_t)N * 8                               // cnt2
                + 16 + (size_t)nb * 8                         // ticket + partials
                + (size_t)N * 8 + (size_t)N * 4 * 2           // cur2, off_p, off_n
                + 64;

    if (ws_size >= need) {
        char* p = (char*)d_ws;
        unsigned short* w16W = (unsigned short*)p; p += (size_t)N * D * 2;
        unsigned short* w16P = (unsigned short*)p; p += (size_t)N * D * 2;
        int*  ent_p = (int*)p;  p += (size_t)n_entp * 4;
        int*  ent_n = (int*)p;  p += (size_t)n_entn * 4;
        // --- contiguous zeroed region: pad | cnt2 | ticket | partials ---
        char* zbase = p;
        p += 64;
        int2* cnt2  = (int2*)p; p += (size_t)N * 8;
        int*  ticket = (int*)p; p += 16;
        unsigned long long* partials = (unsigned long long*)p; p += (size_t)nb * 8;
        size_t zbytes = (size_t)(p - zbase);
        int2* cur2  = (int2*)p; p += (size_t)N * 8;
        int*  off_p = (int*)p;  p += (size_t)N * 4;
        int*  off_n = (int*)p;

        hipMemsetAsync(zbase, 0, zbytes, stream);
        int n32 = N * 32;
        int cb = (n32 + 255) / 256;
        int hb = (Np + Nn + 255) / 256;
        convhist_kernel<<<cb + hb, 256, 0, stream>>>(W, w16W, n32, cb,
                                                     ipu, ipv, inv, Np, Nn, NEG, cnt2);
        scan_fused<<<nb, 256, 0, stream>>>(cnt2, off_p, off_n, cur2, partials, ticket, N);
        int tot = Np + Nn;
        fill_kernel<<<(tot + 255) / 256, 256, 0, stream>>>(ipu, ipv, inu, inv, Np, Nn, NEG,
                                                           cur2, ent_p, ent_n);

        // batched half-waves: KPH nodes per 32-lane half-wave
        const int KPH = 8;
        int hwTotal = (N + KPH - 1) / KPH;          // half-waves needed
        int ublocks = (hwTotal + 7) / 8;            // 8 half-waves per 256-thr block
        // pos: base=W fp32, partners=bf16(W); write Wpos fp32 -> d_out + bf16 shadow -> w16P
        update_kernel<true><<<ublocks, 256, 0, stream>>>(
            W, w16W, out, w16P, off_p, (const int*)cur2, 0, ent_p, N, KPH, NCE_BIAS, 1.0f);
        // neg: base=own fp32 row of d_out (Wpos), partners=bf16(Wpos); overwrite own row
        update_kernel<false><<<ublocks, 256, 0, stream>>>(
            out, w16P, out, (unsigned short*)nullptr, off_n, (const int*)cur2, 1, ent_n,
            N, KPH, NCE_NEG_BIAS, 0.0f);
    } else {
        // scatter fallback (needs only one W-sized snapshot)
        float* snap = (float*)d_ws;
        hipMemcpyAsync(out, W, WB, hipMemcpyDeviceToDevice, stream);
        int blocks = (Np * 64 + 255) / 256;
        pos_kernel<<<blocks, 256, 0, stream>>>(W, out, lut, ipu, ipv, Np);
        hipMemcpyAsync(snap, out, WB, hipMemcpyDeviceToDevice, stream);
        neg_kernel<<<blocks, 256, 0, stream>>>(snap, out, lut, inu, inv, Np, NEG);
    }
}

// Round 7
// 270.272 us; speedup vs baseline: 1.0703x; 1.0703x over previous
//
#include <hip/hip_runtime.h>
#include <hip/hip_bf16.h>

#define D 128
#define LR 0.025f
#define NCE_BIAS 11.512925464970229f      // log(100000)
#define NCE_NEG_BIAS 9.903487552536127f   // log(100000/5)
#define LUT_SIZE 1202

__device__ __forceinline__ float wave_allreduce(float x) {
    #pragma unroll
    for (int m = 32; m >= 1; m >>= 1) x += __shfl_xor(x, m, 64);
    return x;
}

// Analytic stand-in for the reference's LUT sigmoid (centered quantization err <=1.25e-3).
__device__ __forceinline__ float fast_sig(float x) {
    x = fminf(fmaxf(x, -6.0f), 6.0f) - 0.005f;
    float e = __expf(-x);
    return __builtin_amdgcn_rcpf(1.0f + e);
}

__device__ __forceinline__ float fast_sig_lut(float s, const float* __restrict__ lut) {
    s = fminf(fmaxf(s, -6.0f), 6.0f);
    int idx = (int)floorf((s + 6.01f) / 0.01f);
    idx = min(max(idx, 0), LUT_SIZE - 1);
    return lut[idx];
}

__device__ __forceinline__ unsigned int bf16_rne(float f) {
    unsigned int u = __float_as_uint(f);
    return (u + 0x7FFFu + ((u >> 16) & 1u)) >> 16;
}

// ---------------- degree histogram (conv pass DELETED this round) ----------
// cnt2[i] = {pos_degree, neg_degree}. Pos pair t: ONE 64-bit atomic bumps both
// fields of u (pos +1, neg +NEG — idx_neg_u = repeat(idx_pos_u, NEG)).
__global__ __launch_bounds__(256) void hist_kernel(
    const int* __restrict__ ipu, const int* __restrict__ ipv,
    const int* __restrict__ inv,
    int Np, int Nn, int NEG, int2* __restrict__ cnt2)
{
    int t = blockIdx.x * 256 + threadIdx.x;
    if (t < Np) {
        atomicAdd((unsigned long long*)&cnt2[ipu[t]],
                  1ull + ((unsigned long long)NEG << 32));
        atomicAdd(&cnt2[ipv[t]].x, 1);
    } else if (t < Np + Nn) {
        int k = t - Np;
        atomicAdd(&cnt2[inv[k]].y, 1);
    }
}

// ---------------- single-pass dual exclusive scan (decoupled lookback) ----
__global__ __launch_bounds__(256) void scan_fused(
    const int2* __restrict__ cnt2,
    int* __restrict__ off_p, int* __restrict__ off_n, int2* __restrict__ cur2,
    unsigned long long* __restrict__ partials, int* __restrict__ ticket, int n)
{
    __shared__ int shp[256], shn[256];
    __shared__ int tkt_s;
    if (threadIdx.x == 0) tkt_s = atomicAdd(ticket, 1);
    __syncthreads();
    const int t = tkt_s;

    int g = t * 256 + threadIdx.x;
    int2 x = (g < n) ? cnt2[g] : make_int2(0, 0);
    shp[threadIdx.x] = x.x;
    shn[threadIdx.x] = x.y;
    __syncthreads();
    #pragma unroll
    for (int d = 1; d < 256; d <<= 1) {
        int tp = (threadIdx.x >= d) ? shp[threadIdx.x - d] : 0;
        int tn = (threadIdx.x >= d) ? shn[threadIdx.x - d] : 0;
        __syncthreads();
        shp[threadIdx.x] += tp;
        shn[threadIdx.x] += tn;
        __syncthreads();
    }
    int incP = shp[threadIdx.x];          // inclusive local scan
    int incN = shn[threadIdx.x];

    if (threadIdx.x == 255) {
        unsigned long long v = (unsigned long long)(unsigned int)(incP + 1)
                             | ((unsigned long long)(unsigned int)incN << 32);
        atomicExch(&partials[t], v);      // atomic 64-bit publish (agg+flag in one word)
    }

    // lookback: sum aggregates of all predecessor tickets
    int myP = 0, myN = 0;
    for (int i = threadIdx.x; i < t; i += 256) {
        unsigned long long v;
        do {
            v = atomicAdd(&partials[i], 0ull);     // device-scope atomic read
        } while ((v & 0xFFFFFFFFull) == 0ull);
        myP += (int)(v & 0xFFFFFFFFull) - 1;
        myN += (int)(v >> 32);
    }
    __syncthreads();                       // shp/shn free for reuse
    shp[threadIdx.x] = myP;
    shn[threadIdx.x] = myN;
    __syncthreads();
    #pragma unroll
    for (int d = 128; d > 0; d >>= 1) {
        if (threadIdx.x < d) {
            shp[threadIdx.x] += shp[threadIdx.x + d];
            shn[threadIdx.x] += shn[threadIdx.x + d];
        }
        __syncthreads();
    }
    const int baseP = shp[0];
    const int baseN = shn[0];

    if (g < n) {
        int vp = incP - x.x + baseP;       // exclusive + global base
        int vn = incN - x.y + baseN;
        off_p[g] = vp;
        off_n[g] = vn;
        cur2[g] = make_int2(vp, vn);
    }
}

// pos pair t: ONE 64-bit atomic reserves the u-side pos slot AND NEG contiguous
// neg slots; neg partners written contiguously.
__global__ __launch_bounds__(256) void fill_kernel(
    const int* __restrict__ ipu, const int* __restrict__ ipv,
    const int* __restrict__ inu, const int* __restrict__ inv,
    int Np, int Nn, int NEG,
    int2* __restrict__ cur2, int* __restrict__ ent_p, int* __restrict__ ent_n)
{
    int t = blockIdx.x * 256 + threadIdx.x;
    if (t < Np) {
        int u = ipu[t], v = ipv[t];
        unsigned long long pk = atomicAdd((unsigned long long*)&cur2[u],
                                          1ull + ((unsigned long long)NEG << 32));
        int slot_pu = (int)(pk & 0xFFFFFFFFull);
        int slot_nu = (int)(pk >> 32);
        ent_p[slot_pu] = v;
        for (int j = 0; j < NEG; ++j)
            ent_n[slot_nu + j] = inv[(size_t)NEG * t + j];
        ent_p[atomicAdd(&cur2[v].x, 1)] = u;
    } else if (t < Np + Nn) {
        int k = t - Np;
        ent_n[atomicAdd(&cur2[inv[k]].y, 1)] = inu[k];
    }
}

// ---------------- pull update (R2 exact body; P32 = fp32 partner rows) ----
// Half-wave per node (32 lanes). R2's best-known pipeline (54.4us): 4-wide
// groups, CLAMPED prefetch (overruns re-hit the len-1 row in L1), 64-bit
// indexed addressing, no unroll pragma. Select-exchange multi-reduce with
// bit-identical xor tree (16,8,4,2,1) and accumulation order.
// P32=true (pos pass): partners are fp32 rows of W itself (512B rows,
// float4/lane) — the w16W conv pass is deleted; no bf16 unpack ops.
// P32=false (neg pass): partners are bf16 rows (256B, uint2/lane), as before.
template<bool EMIT16, bool P32>
__global__ __launch_bounds__(256) void update_kernel(
    const float* __restrict__ baseSrc,
    const unsigned short* __restrict__ partnerH,
    const float* __restrict__ partnerF,
    float* __restrict__ dst, unsigned short* __restrict__ dst16,
    const int* __restrict__ offArr, const int* __restrict__ endArr2, int comp,
    const int* __restrict__ entries, int N, float bias, float cpos)
{
    int gtid = blockIdx.x * 256 + threadIdx.x;
    int node = gtid >> 5;
    int hl   = threadIdx.x & 31;
    if (node >= N) return;

    const bool b3 = (hl & 8) != 0;
    const bool b4 = (hl & 16) != 0;
    const int i_lane = (hl >> 3) & 3;   // which entry's dot this lane owns post-reduce
    const uint2*  __restrict__ ph = (const uint2*)partnerH;
    const float4* __restrict__ pf = (const float4*)partnerF;

    float4 base = ((const float4*)baseSrc)[(size_t)node * 32 + hl];
    float ax = 0.0f, ay = 0.0f, az = 0.0f, aw = 0.0f;

    int beg = offArr[node];
    int len = endArr2[2 * node + comp] - beg;

    if (len > 0) {
        int gcount = (len + 3) >> 2;
        int en[4];
        uint2  rcH[4];
        float4 rcF[4];
        #pragma unroll
        for (int i = 0; i < 4; ++i) {
            int t = min(i, len - 1);
            if constexpr (P32) rcF[i] = pf[(size_t)entries[beg + t] * 32 + hl];
            else               rcH[i] = ph[(size_t)entries[beg + t] * 32 + hl];
        }
        #pragma unroll
        for (int i = 0; i < 4; ++i) {
            int t = min(4 + i, len - 1);
            en[i] = entries[beg + t];
        }
        for (int g = 0; g < gcount; ++g) {
            uint2  rnH[4];
            float4 rnF[4];
            #pragma unroll
            for (int i = 0; i < 4; ++i) {
                if constexpr (P32) rnF[i] = pf[(size_t)en[i] * 32 + hl];
                else               rnH[i] = ph[(size_t)en[i] * 32 + hl];
            }
            int en2[4];
            #pragma unroll
            for (int i = 0; i < 4; ++i) {
                int t = (g + 2) * 4 + i;
                t = (t < len) ? t : (len - 1);
                en2[i] = entries[beg + t];
            }
            float4 r[4];
            float d[4];
            #pragma unroll
            for (int i = 0; i < 4; ++i) {
                if constexpr (P32) {
                    r[i] = rcF[i];
                } else {
                    r[i].x = __uint_as_float(rcH[i].x << 16);
                    r[i].y = __uint_as_float(rcH[i].x & 0xFFFF0000u);
                    r[i].z = __uint_as_float(rcH[i].y << 16);
                    r[i].w = __uint_as_float(rcH[i].y & 0xFFFF0000u);
                }
                d[i] = r[i].x * base.x + r[i].y * base.y + r[i].z * base.z + r[i].w * base.w;
            }
            // ---- select-exchange multi-reduce (same xor tree as before) ----
            float y0 = b4 ? d[0] : d[2];
            float y1 = b4 ? d[1] : d[3];
            y0 = __shfl_xor(y0, 16, 64);
            y1 = __shfl_xor(y1, 16, 64);
            float pa = (b4 ? d[2] : d[0]) + y0;
            float pb = (b4 ? d[3] : d[1]) + y1;
            float y2 = b3 ? pa : pb;
            y2 = __shfl_xor(y2, 8, 64);
            float cc = (b3 ? pb : pa) + y2;
            cc += __shfl_xor(cc, 4, 64);
            cc += __shfl_xor(cc, 2, 64);
            cc += __shfl_xor(cc, 1, 64);

            // ---- one score per lane (lane class b4,b3 owns entry 2*b4+b3) ----
            float s = (g * 4 + i_lane < len)
                        ? (cpos - fast_sig(cc - bias)) * LR : 0.0f;

            // ---- broadcast 4 scores to all lanes ----
            float t8  = __shfl_xor(s, 8, 64);
            float t16 = __shfl_xor(s, 16, 64);
            float t24 = __shfl_xor(t8, 16, 64);
            float p  = b3 ? t8  : s;
            float q  = b3 ? s   : t8;
            float p2 = b3 ? t24 : t16;
            float q2 = b3 ? t16 : t24;
            float se[4];
            se[0] = b4 ? p2 : p;
            se[1] = b4 ? q2 : q;
            se[2] = b4 ? p  : p2;
            se[3] = b4 ? q  : q2;

            #pragma unroll
            for (int i = 0; i < 4; ++i) {
                ax += se[i] * r[i].x;
                ay += se[i] * r[i].y;
                az += se[i] * r[i].z;
                aw += se[i] * r[i].w;
            }
            #pragma unroll
            for (int i = 0; i < 4; ++i) {
                if constexpr (P32) rcF[i] = rnF[i]; else rcH[i] = rnH[i];
                en[i] = en2[i];
            }
        }
    }
    float4 o = make_float4(base.x + ax, base.y + ay, base.z + az, base.w + aw);
    ((float4*)dst)[(size_t)node * 32 + hl] = o;
    if (EMIT16) {
        uint2 h;
        h.x = bf16_rne(o.x) | (bf16_rne(o.y) << 16);
        h.y = bf16_rne(o.z) | (bf16_rne(o.w) << 16);
        ((uint2*)dst16)[(size_t)node * 32 + hl] = h;
    }
}

// ---------------- fallback scatter path (round-1, known-good) ----------------
__global__ __launch_bounds__(256) void pos_kernel(
    const float* __restrict__ Worig, float* __restrict__ W,
    const float* __restrict__ lut,
    const int* __restrict__ idx_u, const int* __restrict__ idx_v, int n)
{
    int wave = (int)((blockIdx.x * blockDim.x + threadIdx.x) >> 6);
    int lane = threadIdx.x & 63;
    if (wave >= n) return;
    int u = idx_u[wave];
    int v = idx_v[wave];
    float2 eu = ((const float2*)(Worig + (size_t)u * D))[lane];
    float2 ev = ((const float2*)(Worig + (size_t)v * D))[lane];
    float dot = wave_allreduce(eu.x * ev.x + eu.y * ev.y);
    float s = (1.0f - fast_sig_lut(dot - NCE_BIAS, lut)) * LR;
    float* wu = W + (size_t)u * D;
    float* wv = W + (size_t)v * D;
    atomicAdd(&wu[2 * lane],     s * ev.x);
    atomicAdd(&wu[2 * lane + 1], s * ev.y);
    atomicAdd(&wv[2 * lane],     s * eu.x);
    atomicAdd(&wv[2 * lane + 1], s * eu.y);
}

__global__ __launch_bounds__(256) void neg_kernel(
    const float* __restrict__ Wsnap, float* __restrict__ W,
    const float* __restrict__ lut,
    const int* __restrict__ idx_u, const int* __restrict__ idx_v, int n, int neg)
{
    int wave = (int)((blockIdx.x * blockDim.x + threadIdx.x) >> 6);
    int lane = threadIdx.x & 63;
    if (wave >= n) return;
    int u = idx_u[wave * neg];
    float2 eu = ((const float2*)(Wsnap + (size_t)u * D))[lane];
    float dux = 0.0f, duy = 0.0f;
    for (int j = 0; j < neg; ++j) {
        int v = idx_v[wave * neg + j];
        float2 ev = ((const float2*)(Wsnap + (size_t)v * D))[lane];
        float dot = wave_allreduce(eu.x * ev.x + eu.y * ev.y);
        float s = -fast_sig_lut(dot - NCE_NEG_BIAS, lut) * LR;
        dux += s * ev.x;
        duy += s * ev.y;
        float* wv = W + (size_t)v * D;
        atomicAdd(&wv[2 * lane],     s * eu.x);
        atomicAdd(&wv[2 * lane + 1], s * eu.y);
    }
    float* wu = W + (size_t)u * D;
    atomicAdd(&wu[2 * lane],     dux);
    atomicAdd(&wu[2 * lane + 1], duy);
}

extern "C" void kernel_launch(void* const* d_in, const int* in_sizes, int n_in,
                              void* d_out, int out_size, void* d_ws, size_t ws_size,
                              hipStream_t stream) {
    const float* W   = (const float*)d_in[0];
    const float* lut = (const float*)d_in[1];
    const int* ipu   = (const int*)d_in[2];
    const int* ipv   = (const int*)d_in[3];
    const int* inu   = (const int*)d_in[4];
    const int* inv   = (const int*)d_in[5];
    float* out = (float*)d_out;

    const int N  = in_sizes[0] / D;        // nodes
    const int Np = in_sizes[2];            // positive pairs
    const int Nn = in_sizes[4];            // negative pairs (N*NEG)
    const int NEG = Nn / Np;
    const size_t WB = (size_t)N * D * sizeof(float);
    const int nb = (N + 255) / 256;
    const int n_entp = 2 * Np;
    const int n_entn = NEG * Np + Nn;

    size_t need = (size_t)N * D * 2                           // w16P only (w16W deleted)
                + (size_t)n_entp * 4 + (size_t)n_entn * 4
                + 64                                          // zero pad after ent_n
                + (size_t)N * 8                               // cnt2
                + 16 + (size_t)nb * 8                         // ticket + partials
                + (size_t)N * 8 + (size_t)N * 4 * 2           // cur2, off_p, off_n
                + 64;

    if (ws_size >= need) {
        char* p = (char*)d_ws;
        unsigned short* w16P = (unsigned short*)p; p += (size_t)N * D * 2;
        int*  ent_p = (int*)p;  p += (size_t)n_entp * 4;
        int*  ent_n = (int*)p;  p += (size_t)n_entn * 4;
        // --- contiguous zeroed region: pad | cnt2 | ticket | partials ---
        char* zbase = p;
        p += 64;
        int2* cnt2  = (int2*)p; p += (size_t)N * 8;
        int*  ticket = (int*)p; p += 16;
        unsigned long long* partials = (unsigned long long*)p; p += (size_t)nb * 8;
        size_t zbytes = (size_t)(p - zbase);
        int2* cur2  = (int2*)p; p += (size_t)N * 8;
        int*  off_p = (int*)p;  p += (size_t)N * 4;
        int*  off_n = (int*)p;

        hipMemsetAsync(zbase, 0, zbytes, stream);
        int tot = Np + Nn;
        hist_kernel<<<(tot + 255) / 256, 256, 0, stream>>>(ipu, ipv, inv, Np, Nn, NEG, cnt2);
        scan_fused<<<nb, 256, 0, stream>>>(cnt2, off_p, off_n, cur2, partials, ticket, N);
        fill_kernel<<<(tot + 255) / 256, 256, 0, stream>>>(ipu, ipv, inu, inv, Np, Nn, NEG,
                                                           cur2, ent_p, ent_n);

        int n32 = N * 32;
        int ublocks = (n32 + 255) / 256;
        // pos: base=W fp32, partners=W fp32 (conv pass deleted);
        //      write Wpos fp32 -> d_out + bf16 shadow -> w16P
        update_kernel<true, true><<<ublocks, 256, 0, stream>>>(
            W, (const unsigned short*)nullptr, W, out, w16P,
            off_p, (const int*)cur2, 0, ent_p, N, NCE_BIAS, 1.0f);
        // neg: base=own fp32 row of d_out (Wpos), partners=bf16(Wpos); overwrite own row
        update_kernel<false, false><<<ublocks, 256, 0, stream>>>(
            out, w16P, (const float*)nullptr, out, (unsigned short*)nullptr,
            off_n, (const int*)cur2, 1, ent_n, N, NCE_NEG_BIAS, 0.0f);
    } else {
        // scatter fallback (needs only one W-sized snapshot)
        float* snap = (float*)d_ws;
        hipMemcpyAsync(out, W, WB, hipMemcpyDeviceToDevice, stream);
        int blocks = (Np * 64 + 255) / 256;
        pos_kernel<<<blocks, 256, 0, stream>>>(W, out, lut, ipu, ipv, Np);
        hipMemcpyAsync(snap, out, WB, hipMemcpyDeviceToDevice, stream);
        neg_kernel<<<blocks, 256, 0, stream>>>(snap, out, lut, inu, inv, Np, NEG);
    }
}